// Round 9
// baseline (584.421 us; speedup 1.0000x reference)
//
#include <hip/hip_runtime.h>

typedef unsigned short u16;
typedef __attribute__((ext_vector_type(8))) short bf16x8;
typedef __attribute__((ext_vector_type(4))) float f32x4;

__device__ __forceinline__ float bf2f(u16 u) { return __uint_as_float(((unsigned)u) << 16); }
__device__ __forceinline__ u16 f2bf(float f) {
  unsigned u = __float_as_uint(f);
  u += 0x7fffu + ((u >> 16) & 1u);   // RNE
  return (u16)(u >> 16);
}
__device__ __forceinline__ void bf2x2(unsigned w, float& lo, float& hi) {
  lo = __uint_as_float(w << 16);
  hi = __uint_as_float(w & 0xffff0000u);
}

// ---------------------------------------------------------------------------
// prep: [0,nx) x->XH (hi bf16); then BC1(1024)=[bl1|br1], BC2(512)=[bl2|br2],
// then qctr[0..1] = statN (work-queue counters for the two gat launches).
// ---------------------------------------------------------------------------
__global__ __launch_bounds__(256) void prep_kernel(
    const float* __restrict__ x,
    const float* __restrict__ bl1, const float* __restrict__ br1,
    const float* __restrict__ bl2, const float* __restrict__ br2,
    u16* __restrict__ XH, float* __restrict__ BC1, float* __restrict__ BC2,
    int* __restrict__ qctr, int statN,
    int nx, int total)
{
  int i = blockIdx.x * 256 + threadIdx.x;
  if (i >= total) return;
  if (i < nx) { XH[i] = f2bf(x[i]); return; }
  int j = i - nx;
  if (j < 1024) { BC1[j] = (j < 512) ? bl1[j] : br1[j - 512]; return; }
  if (j < 1536) { int t = j - 1024; BC2[t] = (t < 256) ? bl2[t] : br2[t - 256]; return; }
  qctr[j - 1536] = statN;
}

// ---------------------------------------------------------------------------
// Weight transpose+split via LDS 64x64 tiles (coalesced read AND write).
// Output regions (n-major, k-minor): W1 [1024n][128k] @0 (cols: Wl1|Wr1),
// W2 [512n][512k] @131072 (Wl2|Wr2), Wjk [128n][896k] @393216.
// 124 tile-blocks total.
// ---------------------------------------------------------------------------
__global__ __launch_bounds__(256) void wtrans_kernel(
    const float* __restrict__ Wl1, const float* __restrict__ Wr1,
    const float* __restrict__ Wl2, const float* __restrict__ Wr2,
    const float* __restrict__ Wjk,
    u16* __restrict__ WTH, u16* __restrict__ WTL)
{
  __shared__ float T[64][65];
  int t = blockIdx.x;
  const float *Wa, *Wb; int K, Nhalf, lds, k0, n0; size_t obase;
  if (t < 32) {                 // W1: 2 k-tiles x 16 n-tiles
    int kt = t & 1, nt = t >> 1;
    K = 128; k0 = kt * 64; n0 = nt * 64; obase = 0;
    Wa = Wl1; Wb = Wr1; Nhalf = 512; lds = 512;
  } else if (t < 96) {          // W2: 8 x 8
    t -= 32; int kt = t & 7, nt = t >> 3;
    K = 512; k0 = kt * 64; n0 = nt * 64; obase = 131072;
    Wa = Wl2; Wb = Wr2; Nhalf = 256; lds = 256;
  } else {                      // Wjk: 14 x 2
    t -= 96; int kt = t % 14, nt = t / 14;
    K = 896; k0 = kt * 64; n0 = nt * 64; obase = 393216;
    Wa = Wjk; Wb = nullptr; Nhalf = 128; lds = 128;
  }
  const int tid = threadIdx.x;
  const int c = tid & 63, rbase = tid >> 6;
  {
    int n = n0 + c;
    const float* S = (n < Nhalf) ? Wa : Wb;
    int nn = (n < Nhalf) ? n : n - Nhalf;
#pragma unroll
    for (int r = 0; r < 16; ++r) {
      int kl = rbase + 4 * r;
      T[kl][c] = S[(size_t)(k0 + kl) * lds + nn];
    }
  }
  __syncthreads();
#pragma unroll
  for (int r = 0; r < 16; ++r) {
    int nl = rbase + 4 * r;
    float v = T[c][nl];
    u16 h = f2bf(v);
    size_t o = obase + (size_t)(n0 + nl) * K + k0 + c;
    WTH[o] = h;
    WTL[o] = f2bf(v - bf2f(h));
  }
}

// ---------------------------------------------------------------------------
// CSR build: histogram -> exclusive scan (shuffle) -> scatter srcs by dst
// ---------------------------------------------------------------------------
__global__ __launch_bounds__(256) void hist_kernel(
    const int* __restrict__ ei, int E, int ET, int* __restrict__ cnt)
{
  int e = blockIdx.x * 256 + threadIdx.x;
  if (e >= ET) return;
  int d = (e < E) ? ei[E + e] : (e - E);
  atomicAdd(&cnt[d], 1);
}

__global__ __launch_bounds__(1024) void scan_kernel(
    const int* __restrict__ cnt, int* __restrict__ rowptr, int n)
{
  __shared__ int wsum[16];
  __shared__ int carry;
  const int tid = threadIdx.x, lane = tid & 63, wv = tid >> 6;
  if (tid == 0) carry = 0;
  __syncthreads();
  for (int base = 0; base < n; base += 1024) {
    int i = base + tid;
    int v = (i < n) ? cnt[i] : 0;
    int s = v;
#pragma unroll
    for (int ofs = 1; ofs < 64; ofs <<= 1) {
      int t = __shfl_up(s, ofs);
      if (lane >= ofs) s += t;
    }
    if (lane == 63) wsum[wv] = s;
    __syncthreads();
    if (wv == 0 && lane < 16) {
      int t = wsum[lane];
#pragma unroll
      for (int ofs = 1; ofs < 16; ofs <<= 1) {
        int u = __shfl_up(t, ofs);
        if (lane >= ofs) t += u;
      }
      wsum[lane] = t;
    }
    __syncthreads();
    int waveoff = (wv == 0) ? 0 : wsum[wv - 1];
    if (i < n) rowptr[i] = carry + waveoff + s - v;
    int tot = wsum[15];
    __syncthreads();
    if (tid == 0) carry += tot;
    __syncthreads();
  }
  if (threadIdx.x == 0) rowptr[n] = carry;
}

__global__ __launch_bounds__(256) void scatter_kernel(
    const int* __restrict__ ei, int E, int ET,
    const int* __restrict__ rowptr, int* __restrict__ cur, int* __restrict__ srcs)
{
  int e = blockIdx.x * 256 + threadIdx.x;
  if (e >= ET) return;
  int s, d;
  if (e < E) { s = ei[e]; d = ei[E + e]; } else { s = e - E; d = s; }
  int pos = rowptr[d] + atomicAdd(&cur[d], 1);
  srcs[pos] = s;
}

// ---------------------------------------------------------------------------
// GEMM v6: 1D grid, XCD-swizzled (the NT n-tiles of one m-tile share an XCD:
// ids with equal residue mod 8). Block = 4 waves, each RW*16 rows x 128 cols.
// B TRANSPOSED (BT[n][k], stride ldbt), double-buffered LDS, A from global.
// ---------------------------------------------------------------------------
template<bool BF16OUT, int RW>
__global__ __launch_bounds__(256, 2) void gemm3t_kernel(
    const u16* __restrict__ A0, int lda0, int K0,
    const u16* __restrict__ A1, int lda1, int K1,
    const u16* __restrict__ A2, int lda2, int K2,
    const u16* __restrict__ BT0, const u16* __restrict__ BT1, const u16* __restrict__ BT2,
    int ldbt,
    const float* __restrict__ bias,
    void* __restrict__ Cv, int ldc,
    int M, int MT, int NT)
{
  // swizzle decode: groups of 8 m-tiles x NT n-tiles
  const int bid = blockIdx.x;
  const int g  = bid / (8 * NT);
  const int rr = bid % (8 * NT);
  const int nt = rr >> 3;
  const int mt = g * 8 + (rr & 7);
  if (mt >= MT) return;

  __shared__ u16 ldsB[2][128 * 40];
  const int tid  = threadIdx.x;
  const int lane = tid & 63;
  const int wid  = tid >> 6;
  const int quad = lane >> 4;
  const int r16  = lane & 15;
  const int m0   = mt * (RW * 64);
  const int n0   = nt * 128;

  f32x4 acc[RW][8];
#pragma unroll
  for (int h = 0; h < RW; ++h)
#pragma unroll
    for (int nc = 0; nc < 8; ++nc) acc[h][nc] = (f32x4){0.f, 0.f, 0.f, 0.f};

  const u16* As[3]  = {A0, A1, A2};
  const u16* BTs[3] = {BT0, BT1, BT2};
  const int  Ks[3]  = {K0, K1, K2};
  const int  lds_[3] = {lda0, lda1, lda2};

  const int srow = tid >> 2;
  const int skq  = (tid & 3) * 8;

#pragma unroll
  for (int s = 0; s < 3; ++s) {
    const int K = Ks[s];
    if (K == 0) continue;
    const u16* A  = As[s];
    const u16* BT = BTs[s];
    const int lda = lds_[s];
    const u16* ap[RW];
#pragma unroll
    for (int h = 0; h < RW; ++h) {
      int ar = m0 + wid * (RW * 16) + h * 16 + r16;
      if (ar >= M) ar = M - 1;
      ap[h] = A + (size_t)ar * lda + quad * 8;
    }
    const u16* bs0 = BT + (size_t)(n0 + srow) * ldbt + skq;
    const u16* bs1 = BT + (size_t)(n0 + 64 + srow) * ldbt + skq;

    uint4 t0 = *reinterpret_cast<const uint4*>(bs0);
    uint4 t1 = *reinterpret_cast<const uint4*>(bs1);
    __syncthreads();
    *reinterpret_cast<uint4*>(&ldsB[0][srow * 40 + skq])        = t0;
    *reinterpret_cast<uint4*>(&ldsB[0][(64 + srow) * 40 + skq]) = t1;
    __syncthreads();

    int cur = 0;
    for (int k0 = 0; k0 < K; k0 += 32) {
      const bool more = (k0 + 32 < K);
      uint4 n0v, n1v;
      if (more) {
        n0v = *reinterpret_cast<const uint4*>(bs0 + k0 + 32);
        n1v = *reinterpret_cast<const uint4*>(bs1 + k0 + 32);
      }
      bf16x8 a[RW];
#pragma unroll
      for (int h = 0; h < RW; ++h)
        a[h] = *reinterpret_cast<const bf16x8*>(ap[h] + k0);
#pragma unroll
      for (int nc = 0; nc < 8; ++nc) {
        bf16x8 b = *reinterpret_cast<const bf16x8*>(&ldsB[cur][(nc * 16 + r16) * 40 + quad * 8]);
#pragma unroll
        for (int h = 0; h < RW; ++h)
          acc[h][nc] = __builtin_amdgcn_mfma_f32_16x16x32_bf16(a[h], b, acc[h][nc], 0, 0, 0);
      }
      if (more) {
        *reinterpret_cast<uint4*>(&ldsB[cur ^ 1][srow * 40 + skq])        = n0v;
        *reinterpret_cast<uint4*>(&ldsB[cur ^ 1][(64 + srow) * 40 + skq]) = n1v;
        __syncthreads();
        cur ^= 1;
      }
    }
  }

#pragma unroll
  for (int nc = 0; nc < 8; ++nc) {
    const int col = n0 + nc * 16 + r16;
    const float bv = bias ? bias[col] : 0.f;
#pragma unroll
    for (int h = 0; h < RW; ++h) {
#pragma unroll
      for (int r = 0; r < 4; ++r) {
        int m = m0 + wid * (RW * 16) + h * 16 + quad * 4 + r;
        if (m < M) {
          float v = acc[h][nc][r] + bv;
          if (BF16OUT) ((u16*)Cv)[(size_t)m * ldc + col] = f2bf(v);
          else         ((float*)Cv)[(size_t)m * ldc + col] = v;
        }
      }
    }
  }
}

// ---------------------------------------------------------------------------
// Fused GATv2 aggregation: one wave per dst node, work-queue scheduled.
// Softmax referenced to the FIRST edge's logit (shift-invariant; no online
// max/rescale). lrelu folded into dot: lrelu(v)*att = (0.6att)v + (0.4att)|v|.
// XLR row (u16): [xl(0..D-1) | xr(D..2D-1)].
// ---------------------------------------------------------------------------
template<int VPL>
__device__ __forceinline__ void load_row(const u16* p, float* dst) {
  if constexpr (VPL == 8) {
    uint4 t = *reinterpret_cast<const uint4*>(p);
    bf2x2(t.x, dst[0], dst[1]); bf2x2(t.y, dst[2], dst[3]);
    bf2x2(t.z, dst[4], dst[5]); bf2x2(t.w, dst[6], dst[7]);
  } else {
    uint2 t = *reinterpret_cast<const uint2*>(p);
    bf2x2(t.x, dst[0], dst[1]); bf2x2(t.y, dst[2], dst[3]);
  }
}

template<int C>
__global__ __launch_bounds__(256) void gat_node_kernel(
    const u16* __restrict__ XLR,
    const int* __restrict__ rowptr, const int* __restrict__ srcs,
    const float* __restrict__ att, const float* __restrict__ bias,
    u16* __restrict__ Hh, int Nn, int* __restrict__ qctr)
{
  constexpr int D = C * 8;
  constexpr int VPL = D / 64;
  const int lane = threadIdx.x & 63;
  const int wv  = (blockIdx.x * 256 + threadIdx.x) >> 6;

  float c1[VPL], c2[VPL], biasR[VPL];
#pragma unroll
  for (int w = 0; w < VPL; ++w) {
    float a = att[lane * VPL + w];
    c1[w] = 0.6f * a;
    c2[w] = 0.4f * a;
    biasR[w] = bias[lane * VPL + w];
  }

  int base = wv * 2;
  while (base < Nn) {
    const int dend = (base + 2 < Nn) ? base + 2 : Nn;
    for (int d = base; d < dend; ++d) {
      float xr[VPL];
      load_row<VPL>(XLR + (size_t)d * (2 * D) + D + lane * VPL, xr);

      const int jb = rowptr[d], je = rowptr[d + 1];

      // first edge = softmax reference
      float acc[VPL];
      load_row<VPL>(XLR + (size_t)srcs[jb] * (2 * D) + lane * VPL, acc);
      float p0 = 0.f;
#pragma unroll
      for (int w = 0; w < VPL; ++w) {
        float v = acc[w] + xr[w];
        p0 = fmaf(c1[w], v, fmaf(c2[w], fabsf(v), p0));
      }
      p0 += __shfl_xor(p0, 1);
      p0 += __shfl_xor(p0, 2);
      p0 += __shfl_xor(p0, 4);
      float den = 1.f;

      int j = jb + 1;
      for (; j + 1 < je; j += 2) {
        float xa[VPL], xb[VPL];
        load_row<VPL>(XLR + (size_t)srcs[j]     * (2 * D) + lane * VPL, xa);
        load_row<VPL>(XLR + (size_t)srcs[j + 1] * (2 * D) + lane * VPL, xb);
        float pa = 0.f, pb = 0.f;
#pragma unroll
        for (int w = 0; w < VPL; ++w) {
          float va = xa[w] + xr[w];
          float vb = xb[w] + xr[w];
          pa = fmaf(c1[w], va, fmaf(c2[w], fabsf(va), pa));
          pb = fmaf(c1[w], vb, fmaf(c2[w], fabsf(vb), pb));
        }
        pa += __shfl_xor(pa, 1); pb += __shfl_xor(pb, 1);
        pa += __shfl_xor(pa, 2); pb += __shfl_xor(pb, 2);
        pa += __shfl_xor(pa, 4); pb += __shfl_xor(pb, 4);
        const float ea = __expf(pa - p0);
        const float eb = __expf(pb - p0);
        den += ea + eb;
#pragma unroll
        for (int w = 0; w < VPL; ++w)
          acc[w] = fmaf(ea, xa[w], fmaf(eb, xb[w], acc[w]));
      }
      if (j < je) {
        float xa[VPL];
        load_row<VPL>(XLR + (size_t)srcs[j] * (2 * D) + lane * VPL, xa);
        float pa = 0.f;
#pragma unroll
        for (int w = 0; w < VPL; ++w) {
          float va = xa[w] + xr[w];
          pa = fmaf(c1[w], va, fmaf(c2[w], fabsf(va), pa));
        }
        pa += __shfl_xor(pa, 1);
        pa += __shfl_xor(pa, 2);
        pa += __shfl_xor(pa, 4);
        const float ea = __expf(pa - p0);
        den += ea;
#pragma unroll
        for (int w = 0; w < VPL; ++w) acc[w] = fmaf(ea, xa[w], acc[w]);
      }

      const float inv = 1.f / den;
      u16* hh = Hh + (size_t)d * D + lane * VPL;
#pragma unroll
      for (int w = 0; w < VPL; ++w) {
        float v = fmaf(acc[w], inv, biasR[w]);
        v = v > 0.f ? v : (__expf(v) - 1.f);
        hh[w] = f2bf(v);
      }
    }
    int nb = 0;
    if (lane == 0) nb = atomicAdd(qctr, 2);
    base = __shfl(nb, 0);
  }
}

// ---------------------------------------------------------------------------

extern "C" void kernel_launch(void* const* d_in, const int* in_sizes, int n_in,
                              void* d_out, int out_size, void* d_ws, size_t ws_size,
                              hipStream_t stream) {
  const float* x     = (const float*)d_in[0];
  const int*   ei    = (const int*)d_in[1];
  const float* Wl1   = (const float*)d_in[2];
  const float* bl1   = (const float*)d_in[3];
  const float* Wr1   = (const float*)d_in[4];
  const float* br1   = (const float*)d_in[5];
  const float* att1  = (const float*)d_in[6];
  const float* bias1 = (const float*)d_in[7];
  const float* Wl2   = (const float*)d_in[8];
  const float* bl2   = (const float*)d_in[9];
  const float* Wr2   = (const float*)d_in[10];
  const float* br2   = (const float*)d_in[11];
  const float* att2  = (const float*)d_in[12];
  const float* bias2 = (const float*)d_in[13];
  const float* Wjk   = (const float*)d_in[14];
  const float* bjk   = (const float*)d_in[15];
  float* out = (float*)d_out;

  const int Nn = in_sizes[0] / 128;   // 20000
  const int E  = in_sizes[1] / 2;     // 320000
  const int ET = E + Nn;              // 340000

  const size_t nx = (size_t)Nn * 128;

  const size_t oW1T  = 0;        // [Wl1T|Wr1T]: 1024 rows x 128 k
  const size_t oW2T  = 131072;   // [Wl2T|Wr2T]: 512 rows x 512 k
  const size_t oWjkT = 393216;   // WjkT: 128 rows x 896 k
  const size_t nwsplit = 507904;

  // workspace (~85 MB)
  char* ws = (char*)d_ws;
  size_t off = 0;
  u16* XH  = (u16*)(ws + off); off += nx * 2;
  u16* WTH = (u16*)(ws + off); off += nwsplit * 2;
  u16* WTL = (u16*)(ws + off); off += nwsplit * 2;
  float* BC1 = (float*)(ws + off); off += 1024 * 4;
  float* BC2 = (float*)(ws + off); off += 512 * 4;
  int* qctr  = (int*)(ws + off); off += 16;   // [0]=layer1, [1]=layer2
  u16* XLR1 = (u16*)(ws + off);               // [N][1024] bf16
  u16* XLR2 = XLR1;                           // [N][512]  (sequential reuse)
  off += (size_t)Nn * 1024 * 2;
  u16* H1h = (u16*)(ws + off); off += (size_t)Nn * 512 * 2;
  u16* H2h = (u16*)(ws + off); off += (size_t)Nn * 256 * 2;
  int* rowptr = (int*)(ws + off); off += (size_t)(Nn + 1) * 4;
  int* cur    = (int*)(ws + off); off += (size_t)Nn * 4;
  int* srcs   = (int*)(ws + off); off += (size_t)ET * 4;

  const int nodeblocks = 2048;
  const int statN = nodeblocks * 4 * 2;   // static pair coverage (16384)

  // ---------------- prep + weight transpose + CSR build ----------------
  const int nprep = (int)(nx + 1538);
  prep_kernel<<<(nprep + 255) / 256, 256, 0, stream>>>(
      x, bl1, br1, bl2, br2, XH, BC1, BC2, qctr, statN, (int)nx, nprep);
  wtrans_kernel<<<124, 256, 0, stream>>>(Wl1, Wr1, Wl2, Wr2, Wjk, WTH, WTL);
  hipMemsetAsync(cur, 0, (size_t)Nn * 4, stream);
  hist_kernel<<<(ET + 255) / 256, 256, 0, stream>>>(ei, E, ET, cur);
  scan_kernel<<<1, 1024, 0, stream>>>(cur, rowptr, Nn);
  hipMemsetAsync(cur, 0, (size_t)Nn * 4, stream);
  scatter_kernel<<<(ET + 255) / 256, 256, 0, stream>>>(ei, E, ET, rowptr, cur, srcs);

  // grid sizes (1D, XCD-swizzled): ceil(MT/8)*8*NT
  const int MT4 = (Nn + 255) / 256;   // RW=4 m-tiles: 79
  const int MT1 = (Nn + 63) / 64;     // RW=1 m-tiles: 313
  const int g1 = ((MT4 + 7) / 8) * 8 * 8;   // 640
  const int g2 = ((MT4 + 7) / 8) * 8 * 4;   // 320
  const int g3 = ((MT1 + 7) / 8) * 8 * 1;   // 320

  // ---------------- Layer 1: XLR1 = XH @ [Wl1|Wr1] (2-term split) ----------
  gemm3t_kernel<true, 4><<<g1, 256, 0, stream>>>(
      XH, 128, 128, XH, 128, 128, nullptr, 0, 0,
      WTH + oW1T, WTL + oW1T, nullptr, 128, BC1,
      XLR1, 1024, Nn, MT4, 8);
  gat_node_kernel<64><<<nodeblocks, 256, 0, stream>>>(
      XLR1, rowptr, srcs, att1, bias1, H1h, Nn, qctr);

  // ---------------- Layer 2: XLR2 = H1h @ [Wl2|Wr2] (2-term split) ---------
  gemm3t_kernel<true, 4><<<g2, 256, 0, stream>>>(
      H1h, 512, 512, H1h, 512, 512, nullptr, 0, 0,
      WTH + oW2T, WTL + oW2T, nullptr, 512, BC2,
      XLR2, 512, Nn, MT4, 4);
  gat_node_kernel<32><<<nodeblocks, 256, 0, stream>>>(
      XLR2, rowptr, srcs, att2, bias2, H2h, Nn, qctr + 1);

  // ---------------- JK linear: out = [x|h1|h2] @ Wjk + bjk (hi-only) -------
  gemm3t_kernel<false, 1><<<g3, 256, 0, stream>>>(
      XH, 128, 128, H1h, 512, 512, H2h, 256, 256,
      WTH + oWjkT, WTH + oWjkT + 128, WTH + oWjkT + 640, 896, bjk,
      out, 128, Nn, MT1, 1);
}

// Round 10
// 400.842 us; speedup vs baseline: 1.4580x; 1.4580x over previous
//
#include <hip/hip_runtime.h>

typedef unsigned short u16;
typedef __attribute__((ext_vector_type(8))) short bf16x8;
typedef __attribute__((ext_vector_type(4))) float f32x4;

__device__ __forceinline__ float bf2f(u16 u) { return __uint_as_float(((unsigned)u) << 16); }
__device__ __forceinline__ u16 f2bf(float f) {
  unsigned u = __float_as_uint(f);
  u += 0x7fffu + ((u >> 16) & 1u);   // RNE
  return (u16)(u >> 16);
}
__device__ __forceinline__ void bf2x2(unsigned w, float& lo, float& hi) {
  lo = __uint_as_float(w << 16);
  hi = __uint_as_float(w & 0xffff0000u);
}

// ---------------------------------------------------------------------------
// prep: [0,nx) x->XH (hi bf16); then BC1(1024)=[bl1|br1], BC2(512)=[bl2|br2].
// ---------------------------------------------------------------------------
__global__ __launch_bounds__(256) void prep_kernel(
    const float* __restrict__ x,
    const float* __restrict__ bl1, const float* __restrict__ br1,
    const float* __restrict__ bl2, const float* __restrict__ br2,
    u16* __restrict__ XH, float* __restrict__ BC1, float* __restrict__ BC2,
    int nx, int total)
{
  int i = blockIdx.x * 256 + threadIdx.x;
  if (i >= total) return;
  if (i < nx) { XH[i] = f2bf(x[i]); return; }
  int j = i - nx;
  if (j < 1024) { BC1[j] = (j < 512) ? bl1[j] : br1[j - 512]; return; }
  int t = j - 1024;
  BC2[t] = (t < 256) ? bl2[t] : br2[t - 256];
}

// ---------------------------------------------------------------------------
// Weight transpose+split via LDS 64x64 tiles (coalesced read AND write).
// Output regions (n-major, k-minor): W1 [1024n][128k] @0 (cols: Wl1|Wr1),
// W2 [512n][512k] @131072 (Wl2|Wr2), Wjk [128n][896k] @393216.
// ---------------------------------------------------------------------------
__global__ __launch_bounds__(256) void wtrans_kernel(
    const float* __restrict__ Wl1, const float* __restrict__ Wr1,
    const float* __restrict__ Wl2, const float* __restrict__ Wr2,
    const float* __restrict__ Wjk,
    u16* __restrict__ WTH, u16* __restrict__ WTL)
{
  __shared__ float T[64][65];
  int t = blockIdx.x;
  const float *Wa, *Wb; int K, Nhalf, lds, k0, n0; size_t obase;
  if (t < 32) {                 // W1: 2 k-tiles x 16 n-tiles
    int kt = t & 1, nt = t >> 1;
    K = 128; k0 = kt * 64; n0 = nt * 64; obase = 0;
    Wa = Wl1; Wb = Wr1; Nhalf = 512; lds = 512;
  } else if (t < 96) {          // W2: 8 x 8
    t -= 32; int kt = t & 7, nt = t >> 3;
    K = 512; k0 = kt * 64; n0 = nt * 64; obase = 131072;
    Wa = Wl2; Wb = Wr2; Nhalf = 256; lds = 256;
  } else {                      // Wjk: 14 x 2
    t -= 96; int kt = t % 14, nt = t / 14;
    K = 896; k0 = kt * 64; n0 = nt * 64; obase = 393216;
    Wa = Wjk; Wb = nullptr; Nhalf = 128; lds = 128;
  }
  const int tid = threadIdx.x;
  const int c = tid & 63, rbase = tid >> 6;
  {
    int n = n0 + c;
    const float* S = (n < Nhalf) ? Wa : Wb;
    int nn = (n < Nhalf) ? n : n - Nhalf;
#pragma unroll
    for (int r = 0; r < 16; ++r) {
      int kl = rbase + 4 * r;
      T[kl][c] = S[(size_t)(k0 + kl) * lds + nn];
    }
  }
  __syncthreads();
#pragma unroll
  for (int r = 0; r < 16; ++r) {
    int nl = rbase + 4 * r;
    float v = T[c][nl];
    u16 h = f2bf(v);
    size_t o = obase + (size_t)(n0 + nl) * K + k0 + c;
    WTH[o] = h;
    WTL[o] = f2bf(v - bf2f(h));
  }
}

// ---------------------------------------------------------------------------
// CSR build: histogram -> exclusive scan (shuffle) -> scatter srcs by dst
// ---------------------------------------------------------------------------
__global__ __launch_bounds__(256) void hist_kernel(
    const int* __restrict__ ei, int E, int ET, int* __restrict__ cnt)
{
  int e = blockIdx.x * 256 + threadIdx.x;
  if (e >= ET) return;
  int d = (e < E) ? ei[E + e] : (e - E);
  atomicAdd(&cnt[d], 1);
}

__global__ __launch_bounds__(1024) void scan_kernel(
    const int* __restrict__ cnt, int* __restrict__ rowptr, int n)
{
  __shared__ int wsum[16];
  __shared__ int carry;
  const int tid = threadIdx.x, lane = tid & 63, wv = tid >> 6;
  if (tid == 0) carry = 0;
  __syncthreads();
  for (int base = 0; base < n; base += 1024) {
    int i = base + tid;
    int v = (i < n) ? cnt[i] : 0;
    int s = v;
#pragma unroll
    for (int ofs = 1; ofs < 64; ofs <<= 1) {
      int t = __shfl_up(s, ofs);
      if (lane >= ofs) s += t;
    }
    if (lane == 63) wsum[wv] = s;
    __syncthreads();
    if (wv == 0 && lane < 16) {
      int t = wsum[lane];
#pragma unroll
      for (int ofs = 1; ofs < 16; ofs <<= 1) {
        int u = __shfl_up(t, ofs);
        if (lane >= ofs) t += u;
      }
      wsum[lane] = t;
    }
    __syncthreads();
    int waveoff = (wv == 0) ? 0 : wsum[wv - 1];
    if (i < n) rowptr[i] = carry + waveoff + s - v;
    int tot = wsum[15];
    __syncthreads();
    if (tid == 0) carry += tot;
    __syncthreads();
  }
  if (threadIdx.x == 0) rowptr[n] = carry;
}

__global__ __launch_bounds__(256) void scatter_kernel(
    const int* __restrict__ ei, int E, int ET,
    const int* __restrict__ rowptr, int* __restrict__ cur, int* __restrict__ srcs)
{
  int e = blockIdx.x * 256 + threadIdx.x;
  if (e >= ET) return;
  int s, d;
  if (e < E) { s = ei[e]; d = ei[E + e]; } else { s = e - E; d = s; }
  int pos = rowptr[d] + atomicAdd(&cur[d], 1);
  srcs[pos] = s;
}

// ---------------------------------------------------------------------------
// GEMM (round-8 known-good): C[M, 0:Nc] = sum_s A_s[M,K_s] @ B_s + bias.
// B TRANSPOSED (BT[n][k], stride ldbt). 2D grid; block = 4 waves, each wave
// RW*16 rows x 128 cols. B-tile (128n x 32k) double-buffered in LDS via
// uint4; one barrier per k-step. A fragments from global (16B/lane).
// ---------------------------------------------------------------------------
template<bool BF16OUT, int RW>
__global__ __launch_bounds__(256, 2) void gemm3t_kernel(
    const u16* __restrict__ A0, int lda0, int K0,
    const u16* __restrict__ A1, int lda1, int K1,
    const u16* __restrict__ A2, int lda2, int K2,
    const u16* __restrict__ BT0, const u16* __restrict__ BT1, const u16* __restrict__ BT2,
    int ldbt,
    const float* __restrict__ bias,
    void* __restrict__ Cv, int ldc,
    int M)
{
  __shared__ u16 ldsB[2][128 * 40];
  const int tid  = threadIdx.x;
  const int lane = tid & 63;
  const int wid  = tid >> 6;
  const int quad = lane >> 4;
  const int r16  = lane & 15;
  const int m0   = blockIdx.x * (RW * 64);
  const int n0   = blockIdx.y * 128;

  f32x4 acc[RW][8];
#pragma unroll
  for (int h = 0; h < RW; ++h)
#pragma unroll
    for (int nc = 0; nc < 8; ++nc) acc[h][nc] = (f32x4){0.f, 0.f, 0.f, 0.f};

  const u16* As[3]  = {A0, A1, A2};
  const u16* BTs[3] = {BT0, BT1, BT2};
  const int  Ks[3]  = {K0, K1, K2};
  const int  lds_[3] = {lda0, lda1, lda2};

  const int srow = tid >> 2;
  const int skq  = (tid & 3) * 8;

#pragma unroll
  for (int s = 0; s < 3; ++s) {
    const int K = Ks[s];
    if (K == 0) continue;
    const u16* A  = As[s];
    const u16* BT = BTs[s];
    const int lda = lds_[s];
    const u16* ap[RW];
#pragma unroll
    for (int h = 0; h < RW; ++h) {
      int ar = m0 + wid * (RW * 16) + h * 16 + r16;
      if (ar >= M) ar = M - 1;
      ap[h] = A + (size_t)ar * lda + quad * 8;
    }
    const u16* bs0 = BT + (size_t)(n0 + srow) * ldbt + skq;
    const u16* bs1 = BT + (size_t)(n0 + 64 + srow) * ldbt + skq;

    uint4 t0 = *reinterpret_cast<const uint4*>(bs0);
    uint4 t1 = *reinterpret_cast<const uint4*>(bs1);
    __syncthreads();
    *reinterpret_cast<uint4*>(&ldsB[0][srow * 40 + skq])        = t0;
    *reinterpret_cast<uint4*>(&ldsB[0][(64 + srow) * 40 + skq]) = t1;
    __syncthreads();

    int cur = 0;
    for (int k0 = 0; k0 < K; k0 += 32) {
      const bool more = (k0 + 32 < K);
      uint4 n0v, n1v;
      if (more) {
        n0v = *reinterpret_cast<const uint4*>(bs0 + k0 + 32);
        n1v = *reinterpret_cast<const uint4*>(bs1 + k0 + 32);
      }
      bf16x8 a[RW];
#pragma unroll
      for (int h = 0; h < RW; ++h)
        a[h] = *reinterpret_cast<const bf16x8*>(ap[h] + k0);
#pragma unroll
      for (int nc = 0; nc < 8; ++nc) {
        bf16x8 b = *reinterpret_cast<const bf16x8*>(&ldsB[cur][(nc * 16 + r16) * 40 + quad * 8]);
#pragma unroll
        for (int h = 0; h < RW; ++h)
          acc[h][nc] = __builtin_amdgcn_mfma_f32_16x16x32_bf16(a[h], b, acc[h][nc], 0, 0, 0);
      }
      if (more) {
        *reinterpret_cast<uint4*>(&ldsB[cur ^ 1][srow * 40 + skq])        = n0v;
        *reinterpret_cast<uint4*>(&ldsB[cur ^ 1][(64 + srow) * 40 + skq]) = n1v;
        __syncthreads();
        cur ^= 1;
      }
    }
  }

#pragma unroll
  for (int nc = 0; nc < 8; ++nc) {
    const int col = n0 + nc * 16 + r16;
    const float bv = bias ? bias[col] : 0.f;
#pragma unroll
    for (int h = 0; h < RW; ++h) {
#pragma unroll
      for (int r = 0; r < 4; ++r) {
        int m = m0 + wid * (RW * 16) + h * 16 + quad * 4 + r;
        if (m < M) {
          float v = acc[h][nc][r] + bv;
          if (BF16OUT) ((u16*)Cv)[(size_t)m * ldc + col] = f2bf(v);
          else         ((float*)Cv)[(size_t)m * ldc + col] = v;
        }
      }
    }
  }
}

// ---------------------------------------------------------------------------
// Fused GATv2 aggregation: one wave per dst node, STATIC stride schedule
// (5000 waves x exactly 4 nodes). Softmax referenced to first edge's logit.
// lrelu folded into dot: lrelu(v)*att = (0.6att)v + (0.4att)|v|.
// XLR row (u16): [xl(0..D-1) | xr(D..2D-1)].
// ---------------------------------------------------------------------------
template<int VPL>
__device__ __forceinline__ void load_row(const u16* p, float* dst) {
  if constexpr (VPL == 8) {
    uint4 t = *reinterpret_cast<const uint4*>(p);
    bf2x2(t.x, dst[0], dst[1]); bf2x2(t.y, dst[2], dst[3]);
    bf2x2(t.z, dst[4], dst[5]); bf2x2(t.w, dst[6], dst[7]);
  } else {
    uint2 t = *reinterpret_cast<const uint2*>(p);
    bf2x2(t.x, dst[0], dst[1]); bf2x2(t.y, dst[2], dst[3]);
  }
}

template<int C>
__global__ __launch_bounds__(256) void gat_node_kernel(
    const u16* __restrict__ XLR,
    const int* __restrict__ rowptr, const int* __restrict__ srcs,
    const float* __restrict__ att, const float* __restrict__ bias,
    u16* __restrict__ Hh, int Nn)
{
  constexpr int D = C * 8;
  constexpr int VPL = D / 64;
  const int lane = threadIdx.x & 63;
  const int wv  = (blockIdx.x * 256 + threadIdx.x) >> 6;
  const int nwv = (gridDim.x * 256) >> 6;

  float c1[VPL], c2[VPL], biasR[VPL];
#pragma unroll
  for (int w = 0; w < VPL; ++w) {
    float a = att[lane * VPL + w];
    c1[w] = 0.6f * a;
    c2[w] = 0.4f * a;
    biasR[w] = bias[lane * VPL + w];
  }

  for (int d = wv; d < Nn; d += nwv) {
    float xr[VPL];
    load_row<VPL>(XLR + (size_t)d * (2 * D) + D + lane * VPL, xr);

    const int jb = rowptr[d], je = rowptr[d + 1];

    // first edge = softmax reference
    float acc[VPL];
    load_row<VPL>(XLR + (size_t)srcs[jb] * (2 * D) + lane * VPL, acc);
    float p0 = 0.f;
#pragma unroll
    for (int w = 0; w < VPL; ++w) {
      float v = acc[w] + xr[w];
      p0 = fmaf(c1[w], v, fmaf(c2[w], fabsf(v), p0));
    }
    p0 += __shfl_xor(p0, 1);
    p0 += __shfl_xor(p0, 2);
    p0 += __shfl_xor(p0, 4);
    float den = 1.f;

    int j = jb + 1;
    for (; j + 1 < je; j += 2) {
      float xa[VPL], xb[VPL];
      load_row<VPL>(XLR + (size_t)srcs[j]     * (2 * D) + lane * VPL, xa);
      load_row<VPL>(XLR + (size_t)srcs[j + 1] * (2 * D) + lane * VPL, xb);
      float pa = 0.f, pb = 0.f;
#pragma unroll
      for (int w = 0; w < VPL; ++w) {
        float va = xa[w] + xr[w];
        float vb = xb[w] + xr[w];
        pa = fmaf(c1[w], va, fmaf(c2[w], fabsf(va), pa));
        pb = fmaf(c1[w], vb, fmaf(c2[w], fabsf(vb), pb));
      }
      pa += __shfl_xor(pa, 1); pb += __shfl_xor(pb, 1);
      pa += __shfl_xor(pa, 2); pb += __shfl_xor(pb, 2);
      pa += __shfl_xor(pa, 4); pb += __shfl_xor(pb, 4);
      const float ea = __expf(pa - p0);
      const float eb = __expf(pb - p0);
      den += ea + eb;
#pragma unroll
      for (int w = 0; w < VPL; ++w)
        acc[w] = fmaf(ea, xa[w], fmaf(eb, xb[w], acc[w]));
    }
    if (j < je) {
      float xa[VPL];
      load_row<VPL>(XLR + (size_t)srcs[j] * (2 * D) + lane * VPL, xa);
      float pa = 0.f;
#pragma unroll
      for (int w = 0; w < VPL; ++w) {
        float va = xa[w] + xr[w];
        pa = fmaf(c1[w], va, fmaf(c2[w], fabsf(va), pa));
      }
      pa += __shfl_xor(pa, 1);
      pa += __shfl_xor(pa, 2);
      pa += __shfl_xor(pa, 4);
      const float ea = __expf(pa - p0);
      den += ea;
#pragma unroll
      for (int w = 0; w < VPL; ++w) acc[w] = fmaf(ea, xa[w], acc[w]);
    }

    const float inv = 1.f / den;
    u16* hh = Hh + (size_t)d * D + lane * VPL;
#pragma unroll
    for (int w = 0; w < VPL; ++w) {
      float v = fmaf(acc[w], inv, biasR[w]);
      v = v > 0.f ? v : (__expf(v) - 1.f);
      hh[w] = f2bf(v);
    }
  }
}

// ---------------------------------------------------------------------------

extern "C" void kernel_launch(void* const* d_in, const int* in_sizes, int n_in,
                              void* d_out, int out_size, void* d_ws, size_t ws_size,
                              hipStream_t stream) {
  const float* x     = (const float*)d_in[0];
  const int*   ei    = (const int*)d_in[1];
  const float* Wl1   = (const float*)d_in[2];
  const float* bl1   = (const float*)d_in[3];
  const float* Wr1   = (const float*)d_in[4];
  const float* br1   = (const float*)d_in[5];
  const float* att1  = (const float*)d_in[6];
  const float* bias1 = (const float*)d_in[7];
  const float* Wl2   = (const float*)d_in[8];
  const float* bl2   = (const float*)d_in[9];
  const float* Wr2   = (const float*)d_in[10];
  const float* br2   = (const float*)d_in[11];
  const float* att2  = (const float*)d_in[12];
  const float* bias2 = (const float*)d_in[13];
  const float* Wjk   = (const float*)d_in[14];
  const float* bjk   = (const float*)d_in[15];
  float* out = (float*)d_out;

  const int Nn = in_sizes[0] / 128;   // 20000
  const int E  = in_sizes[1] / 2;     // 320000
  const int ET = E + Nn;              // 340000

  const size_t nx = (size_t)Nn * 128;

  const size_t oW1T  = 0;        // [Wl1T|Wr1T]: 1024 rows x 128 k
  const size_t oW2T  = 131072;   // [Wl2T|Wr2T]: 512 rows x 512 k
  const size_t oWjkT = 393216;   // WjkT: 128 rows x 896 k
  const size_t nwsplit = 507904;

  // workspace (~85 MB)
  char* ws = (char*)d_ws;
  size_t off = 0;
  u16* XH  = (u16*)(ws + off); off += nx * 2;
  u16* WTH = (u16*)(ws + off); off += nwsplit * 2;
  u16* WTL = (u16*)(ws + off); off += nwsplit * 2;
  float* BC1 = (float*)(ws + off); off += 1024 * 4;
  float* BC2 = (float*)(ws + off); off += 512 * 4;
  u16* XLR1 = (u16*)(ws + off);               // [N][1024] bf16
  u16* XLR2 = XLR1;                           // [N][512]  (sequential reuse)
  off += (size_t)Nn * 1024 * 2;
  u16* H1h = (u16*)(ws + off); off += (size_t)Nn * 512 * 2;
  u16* H2h = (u16*)(ws + off); off += (size_t)Nn * 256 * 2;
  int* rowptr = (int*)(ws + off); off += (size_t)(Nn + 1) * 4;
  int* cur    = (int*)(ws + off); off += (size_t)Nn * 4;
  int* srcs   = (int*)(ws + off); off += (size_t)ET * 4;

  const int nodeblocks = 1250;   // 5000 waves x exactly 4 nodes each

  // ---------------- prep + weight transpose + CSR build ----------------
  const int nprep = (int)(nx + 1536);
  prep_kernel<<<(nprep + 255) / 256, 256, 0, stream>>>(
      x, bl1, br1, bl2, br2, XH, BC1, BC2, (int)nx, nprep);
  wtrans_kernel<<<124, 256, 0, stream>>>(Wl1, Wr1, Wl2, Wr2, Wjk, WTH, WTL);
  hipMemsetAsync(cur, 0, (size_t)Nn * 4, stream);
  hist_kernel<<<(ET + 255) / 256, 256, 0, stream>>>(ei, E, ET, cur);
  scan_kernel<<<1, 1024, 0, stream>>>(cur, rowptr, Nn);
  hipMemsetAsync(cur, 0, (size_t)Nn * 4, stream);
  scatter_kernel<<<(ET + 255) / 256, 256, 0, stream>>>(ei, E, ET, rowptr, cur, srcs);

  const int m256 = (Nn + 255) / 256;   // 79
  const int m64  = (Nn + 63) / 64;     // 313

  // ---------------- Layer 1: XLR1 = XH @ [Wl1|Wr1] (2-term split) ----------
  dim3 g1(m256, 1024 / 128);
  gemm3t_kernel<true, 4><<<g1, 256, 0, stream>>>(
      XH, 128, 128, XH, 128, 128, nullptr, 0, 0,
      WTH + oW1T, WTL + oW1T, nullptr, 128, BC1,
      XLR1, 1024, Nn);
  gat_node_kernel<64><<<nodeblocks, 256, 0, stream>>>(
      XLR1, rowptr, srcs, att1, bias1, H1h, Nn);

  // ---------------- Layer 2: XLR2 = H1h @ [Wl2|Wr2] (2-term split) ---------
  dim3 g2(m256, 512 / 128);
  gemm3t_kernel<true, 4><<<g2, 256, 0, stream>>>(
      H1h, 512, 512, H1h, 512, 512, nullptr, 0, 0,
      WTH + oW2T, WTL + oW2T, nullptr, 512, BC2,
      XLR2, 512, Nn);
  gat_node_kernel<32><<<nodeblocks, 256, 0, stream>>>(
      XLR2, rowptr, srcs, att2, bias2, H2h, Nn);

  // ---------------- JK linear: out = [x|h1|h2] @ Wjk + bjk (hi-only) -------
  dim3 g3(m64, 1);
  gemm3t_kernel<false, 1><<<g3, 256, 0, stream>>>(
      XH, 128, 128, H1h, 512, 512, H2h, 256, 256,
      WTH + oWjkT, WTH + oWjkT + 128, WTH + oWjkT + 640, 896, bjk,
      out, 128, Nn);
}